// Round 7
// baseline (272.619 us; speedup 1.0000x reference)
//
#include <hip/hip_runtime.h>

// RGCN: bucketed atomic-free counting sort + block-local degree-binned
// dim-sliced bf16 gather + pipelined bf16 MFMA GEMM.
// Round-17 (write-locality attack): A-matrix stored SLICE-MAJOR
//   Abuf[4 slices][9 slabs][nNalloc][32]  (slab 8 = x, written once by cvt;
//   slabs 0..7 = agg, written by gather).
//   - gather stores are now 64B CONTIGUOUS per (seg,slice), sequential across
//     segs -> streaming HBM writes (R0..R6 were 64B scattered @256B stride,
//     suspected HBM row-buffer thrash ~ the pinned 60us).
//   - xB/xRow buffers merged into Abuf (cvt writes -12.8 MB).
//   - GEMM staging reads the sliced layout via per-lane source addresses;
//     LDS image + XOR swizzle + ds_read side unchanged.
//
//   seg(e) = rel(e)*nN + src(e)          (numSeg = nRel*nN)
//   agg[seg,:] = bf16( mean_{e in seg} x[dst_e,:] )
//   out = sum_r agg_r @ W_r^T + x @ root^T + bias   (MFMA 16x16x32 bf16)

#define D 128
#define SCAN_CHUNK 2048
#define SEG_BITS 9
#define SEGS_PER_BUCKET 512
#define NBLK 128            // blocks for histA/scatterA
#define NDEG 32             // degree buckets

typedef __attribute__((ext_vector_type(8))) short short8;
typedef __attribute__((ext_vector_type(4))) float v4f;
typedef __attribute__((ext_vector_type(2))) float f32x2;
typedef __attribute__((ext_vector_type(4))) unsigned uint4v;

#define GLOAD_LDS16(gptr, lptr) \
    __builtin_amdgcn_global_load_lds((const __attribute__((address_space(1))) void*)(gptr), \
                                     (__attribute__((address_space(3))) void*)(lptr), 16, 0, 0)

__device__ __forceinline__ unsigned short f2b(float f) {
    union { float f; unsigned u; } v; v.f = f;
    unsigned r = v.u + 0x7fffu + ((v.u >> 16) & 1u);   // RNE
    return (unsigned short)(r >> 16);
}
__device__ __forceinline__ float blo(unsigned u) {
    union { unsigned u; float f; } v; v.u = u << 16; return v.f;
}
__device__ __forceinline__ float bhi(unsigned u) {
    union { unsigned u; float f; } v; v.u = u & 0xffff0000u; return v.f;
}

// ---------- fp32 -> bf16 bulk convert ----------
// x goes to slab 8 of each slice of Abuf: addr = (sl*9 + 8)*SLs + n*32 + (d&31).
// This single copy serves BOTH the gather (L2-resident slice reads) and the
// GEMM (9th A slab).
__global__ void cvt_bf16_all(const float* __restrict__ x, long long nx,
                             const float* __restrict__ w, long long nw,
                             const float* __restrict__ root, long long nr,
                             unsigned short* __restrict__ Abuf,
                             unsigned short* __restrict__ wB, size_t SLs) {
    long long i = ((long long)blockIdx.x * blockDim.x + threadIdx.x) * 4;
    if (i < nx) {
        float4 v = *(const float4*)(x + i);
        uint2 p;
        p.x = (unsigned)f2b(v.x) | ((unsigned)f2b(v.y) << 16);
        p.y = (unsigned)f2b(v.z) | ((unsigned)f2b(v.w) << 16);
        long long n = i >> 7;
        int d = (int)(i & 127);
        size_t o = (size_t)((d >> 5) * 9 + 8) * SLs + (size_t)n * 32 + (d & 31);
        *(uint2*)(Abuf + o) = p;
        return;
    }
    const float* src;
    unsigned short* dst;
    long long j;
    if (i < nx + nw) { src = w; dst = wB; j = i - nx; }
    else if (i < nx + nw + nr) { src = root; dst = wB + nw; j = i - nx - nw; }
    else return;
    float4 v = *(const float4*)(src + j);
    uint2 p;
    p.x = (unsigned)f2b(v.x) | ((unsigned)f2b(v.y) << 16);
    p.y = (unsigned)f2b(v.z) | ((unsigned)f2b(v.w) << 16);
    *(uint2*)(dst + j) = p;
}

// ---------- phase A: per-block bucket histogram (LDS atomics only) ----------
__global__ __launch_bounds__(256)
void histA(const int* __restrict__ ei, const int* __restrict__ et,
           int* __restrict__ blockHist, int nE, int nN, int B, int epb) {
    __shared__ int lh[1024];
    const int tid = threadIdx.x;
    for (int b = tid; b < B; b += 256) lh[b] = 0;
    __syncthreads();
    const int base = blockIdx.x * epb;
    const int lim = min(base + epb, nE);
    for (int e = base + tid; e < lim; e += 256) {
        int seg = et[e] * nN + ei[e];
        atomicAdd(&lh[seg >> SEG_BITS], 1);
    }
    __syncthreads();
    for (int b = tid; b < B; b += 256)
        blockHist[b * NBLK + blockIdx.x] = lh[b];
}

// ---------- scan of blockHist (bucket-major), 2 kernels + inline fixup ----------
__global__ __launch_bounds__(256)
void scan1(const int* __restrict__ in, int* __restrict__ excl,
           int* __restrict__ blockSums, int n) {
    __shared__ int t[256];
    const int tid = threadIdx.x;
    const int base = blockIdx.x * SCAN_CHUNK + tid * 8;
    int v[8];
    int tot = 0;
#pragma unroll
    for (int i = 0; i < 8; i++) {
        v[i] = (base + i < n) ? in[base + i] : 0;
        tot += v[i];
    }
    t[tid] = tot;
    __syncthreads();
    for (int off = 1; off < 256; off <<= 1) {
        int add = (tid >= off) ? t[tid - off] : 0;
        __syncthreads();
        t[tid] += add;
        __syncthreads();
    }
    int run = t[tid] - tot;
#pragma unroll
    for (int i = 0; i < 8; i++) {
        if (base + i < n) excl[base + i] = run;
        run += v[i];
    }
    if (tid == 255) blockSums[blockIdx.x] = t[255];
}

__global__ __launch_bounds__(256)
void scan2(int* __restrict__ blockSums, int nb) {
    __shared__ int t[256];
    const int tid = threadIdx.x;
    int v = (tid < nb) ? blockSums[tid] : 0;
    t[tid] = v;
    __syncthreads();
    for (int off = 1; off < 256; off <<= 1) {
        int add = (tid >= off) ? t[tid - off] : 0;
        __syncthreads();
        t[tid] += add;
        __syncthreads();
    }
    if (tid < nb) blockSums[tid] = t[tid] - v;
}

// ---------- phase C: bucket scatter (adds blockSums fix-up inline) ----------
__global__ __launch_bounds__(256)
void scatterA(const int* __restrict__ ei, const int* __restrict__ et,
              const int* __restrict__ scanned, const int* __restrict__ blockSums,
              unsigned* __restrict__ bucketEdges,
              int nE, int nN, int B, int epb) {
    __shared__ int cur[1024];
    const int tid = threadIdx.x;
    for (int b = tid; b < B; b += 256) {
        int idx = b * NBLK + blockIdx.x;
        cur[b] = scanned[idx] + blockSums[idx >> 11];   // SCAN_CHUNK = 2048
    }
    __syncthreads();
    const int base = blockIdx.x * epb;
    const int lim = min(base + epb, nE);
    for (int e = base + tid; e < lim; e += 256) {
        int seg = et[e] * nN + ei[e];
        int bkt = seg >> SEG_BITS;
        unsigned pk = ((unsigned)(seg & (SEGS_PER_BUCKET - 1)) << 16) | (unsigned)ei[nE + e];
        int pos = atomicAdd(&cur[bkt], 1);
        bucketEdges[pos] = pk;
    }
}

// ---------- phase D: seg offsets + sorted ushort dst + permRec/permMax ----------
// Block-local degree binning (64-seg sub-windows). Writes, at the PERMUTED
// slot, permRec = {start, cnt, seg, 0}, and permMax[chunk] = max degree of
// each 16-seg chunk.
__global__ __launch_bounds__(256)
void segOff(const unsigned* __restrict__ bucketEdges, const int* __restrict__ scanned,
            const int* __restrict__ blockSums,
            int4* __restrict__ permRec, unsigned short* __restrict__ sortedDst,
            int* __restrict__ permMax, int nE, int numSeg, int B) {
    __shared__ int lh[SEGS_PER_BUCKET];
    __shared__ int sc[256];
    __shared__ int lcur[SEGS_PER_BUCKET];
    __shared__ int dcnt[256];    // [sub 0..7][deg 0..31]
    __shared__ int dbase[256];
    __shared__ int smax[32];     // [sub 0..7][chunk 0..3] max degree
    const int tid = threadIdx.x;
    const int b = blockIdx.x;
    const int i0 = b * NBLK;
    const int eBase = scanned[i0] + blockSums[i0 >> 11];
    int eEnd = nE;
    if (b + 1 < B) {
        const int i1 = (b + 1) * NBLK;
        eEnd = scanned[i1] + blockSums[i1 >> 11];
    }
    const int segBase = b * SEGS_PER_BUCKET;
    const int segLim = min(SEGS_PER_BUCKET, numSeg - segBase);

    lh[2 * tid] = 0; lh[2 * tid + 1] = 0;
    dcnt[tid] = 0;
    if (tid < 32) smax[tid] = 0;
    __syncthreads();
    for (int i = eBase + tid; i < eEnd; i += 256)
        atomicAdd(&lh[bucketEdges[i] >> 16], 1);
    __syncthreads();
    const int li0 = 2 * tid, li1 = 2 * tid + 1;
    const int sub = li0 >> 6;            // 64-seg sub-window (== li1>>6)
    int a0 = lh[li0], a1 = lh[li1];
    int b0 = min(a0, NDEG - 1), b1 = min(a1, NDEG - 1), r0 = 0, r1 = 0;
    if (li0 < segLim) r0 = atomicAdd(&dcnt[sub * NDEG + b0], 1);
    if (li1 < segLim) r1 = atomicAdd(&dcnt[sub * NDEG + b1], 1);
    sc[tid] = a0 + a1;
    __syncthreads();
    for (int o = 1; o < 256; o <<= 1) {
        int add = (tid >= o) ? sc[tid - o] : 0;
        __syncthreads();
        sc[tid] += add;
        __syncthreads();
    }
    int pairBase = sc[tid] - (a0 + a1);
    int g0 = eBase + pairBase;
    int g1 = g0 + a0;
    lcur[li0] = g0;
    lcur[li1] = g1;
    if (tid < 8) {               // per-sub serial 32-prefix for bucket bases
        int run = 0;
#pragma unroll
        for (int k = 0; k < NDEG; k++) { dbase[tid * NDEG + k] = run; run += dcnt[tid * NDEG + k]; }
    }
    __syncthreads();
    if (li0 < segLim) {
        int rk = dbase[sub * NDEG + b0] + r0;           // rank within 64-window
        permRec[segBase + sub * 64 + rk] = make_int4(g0, a0, segBase + li0, 0);
        atomicMax(&smax[(sub << 2) + (rk >> 4)], a0);
    }
    if (li1 < segLim) {
        int rk = dbase[sub * NDEG + b1] + r1;
        permRec[segBase + sub * 64 + rk] = make_int4(g1, a1, segBase + li1, 0);
        atomicMax(&smax[(sub << 2) + (rk >> 4)], a1);
    }
    for (int i = eBase + tid; i < eEnd; i += 256) {
        unsigned u = bucketEdges[i];
        int pos = atomicAdd(&lcur[u >> 16], 1);
        sortedDst[pos] = (unsigned short)(u & 0xFFFFu);
    }
    __syncthreads();
    if (tid < 32) permMax[b * 32 + tid] = smax[tid];
}

// ---------- gather: 2 chunks/wave, dim-sliced, 4 lanes/edge ----------
// blockIdx.y = slice (32 dims); per-slice x slab = 3.2 MB -> per-XCD-L2
// resident. Stores are 64B CONTIGUOUS at (sl*9+r)*SLs + n*32 and near-
// sequential across segs -> streaming HBM writes.
__global__ __launch_bounds__(256)
void rgcn_gather(const unsigned short* __restrict__ Abase,
                 const unsigned short* __restrict__ sortedDst,
                 const int4* __restrict__ permRec,
                 const int* __restrict__ permMax,
                 unsigned short* __restrict__ Abuf, int nN, int numSeg,
                 size_t SLs, unsigned long long M) {
    const int tid = threadIdx.x;
    const int lane = tid & 63;
    const int idx4 = lane & 3;       // lane within 4-lane group (8 dims each)
    const int grp = lane >> 2;       // 16 groups per wave
    const int wv = tid >> 6;
    const int gsi0 = blockIdx.x * 128 + wv * 32 + grp;   // chunk 0 of this wave
    const int gsi1 = gsi0 + 16;                          // chunk 1
    const int sl = blockIdx.y;       // dims [sl*32, sl*32+32)
    const bool v0 = (gsi0 < numSeg);
    const bool v1 = (gsi1 < numSeg);

    int4 rc0 = v0 ? permRec[gsi0] : make_int4(0, 0, 0, 0);
    int4 rc1 = v1 ? permRec[gsi1] : make_int4(0, 0, 0, 0);
    int mx0 = v0 ? permMax[gsi0 >> 4] : 0;
    int mx1 = v1 ? permMax[gsi1 >> 4] : 0;
    mx0 = __builtin_amdgcn_readfirstlane(mx0);   // chunk-uniform -> scalar branch
    mx1 = __builtin_amdgcn_readfirstlane(mx1);

    const int start0 = rc0.x, cnt0 = v0 ? rc0.y : 0, seg0 = rc0.z;
    const int start1 = rc1.x, cnt1 = v1 ? rc1.y : 0, seg1 = rc1.z;

    f32x2 a0[4], a1[4];
#pragma unroll
    for (int i = 0; i < 4; i++) { a0[i] = (f32x2){0.f, 0.f}; a1[i] = (f32x2){0.f, 0.f}; }

    // x slab of this slice: slab 8 -> [n][32]; each lane owns 8 consecutive dims
    const unsigned short* xSlab = Abase + (size_t)(sl * 9 + 8) * SLs + idx4 * 8;

    const int mxm = max(mx0, mx1);
    for (int b = 0; b < mxm; b += 4) {
        uint4v w0[4], w1[4];
        int myD0 = 0, myD1 = 0;
        if (b < mx0) myD0 = (b + idx4 < cnt0) ? (int)sortedDst[start0 + b + idx4] : 0;
        if (b < mx1) myD1 = (b + idx4 < cnt1) ? (int)sortedDst[start1 + b + idx4] : 0;
        if (b < mx0) {
#pragma unroll
            for (int j = 0; j < 4; j++) {
                int dst = __shfl(myD0, grp * 4 + j);
                bool act = (b + j < cnt0);
                w0[j] = act ? *(const uint4v*)(xSlab + ((size_t)dst << 5))
                            : (uint4v){0u, 0u, 0u, 0u};
            }
        }
        if (b < mx1) {
#pragma unroll
            for (int j = 0; j < 4; j++) {
                int dst = __shfl(myD1, grp * 4 + j);
                bool act = (b + j < cnt1);
                w1[j] = act ? *(const uint4v*)(xSlab + ((size_t)dst << 5))
                            : (uint4v){0u, 0u, 0u, 0u};
            }
        }
        if (b < mx0) {
#pragma unroll
            for (int j = 0; j < 4; j++) {
                f32x2 t0 = (f32x2){blo(w0[j].x), bhi(w0[j].x)};
                f32x2 t1 = (f32x2){blo(w0[j].y), bhi(w0[j].y)};
                f32x2 t2 = (f32x2){blo(w0[j].z), bhi(w0[j].z)};
                f32x2 t3 = (f32x2){blo(w0[j].w), bhi(w0[j].w)};
                asm("v_pk_add_f32 %0, %0, %1" : "+v"(a0[0]) : "v"(t0));
                asm("v_pk_add_f32 %0, %0, %1" : "+v"(a0[1]) : "v"(t1));
                asm("v_pk_add_f32 %0, %0, %1" : "+v"(a0[2]) : "v"(t2));
                asm("v_pk_add_f32 %0, %0, %1" : "+v"(a0[3]) : "v"(t3));
            }
        }
        if (b < mx1) {
#pragma unroll
            for (int j = 0; j < 4; j++) {
                f32x2 t0 = (f32x2){blo(w1[j].x), bhi(w1[j].x)};
                f32x2 t1 = (f32x2){blo(w1[j].y), bhi(w1[j].y)};
                f32x2 t2 = (f32x2){blo(w1[j].z), bhi(w1[j].z)};
                f32x2 t3 = (f32x2){blo(w1[j].w), bhi(w1[j].w)};
                asm("v_pk_add_f32 %0, %0, %1" : "+v"(a1[0]) : "v"(t0));
                asm("v_pk_add_f32 %0, %0, %1" : "+v"(a1[1]) : "v"(t1));
                asm("v_pk_add_f32 %0, %0, %1" : "+v"(a1[2]) : "v"(t2));
                asm("v_pk_add_f32 %0, %0, %1" : "+v"(a1[3]) : "v"(t3));
            }
        }
    }

    if (v0) {
        float s = cnt0 > 0 ? 1.0f / (float)cnt0 : 0.f;
        const int r = (int)(((unsigned long long)seg0 * M) >> 48);  // seg / nN
        const int n = seg0 - r * nN;
        unsigned p0, p1, p2, p3;
        float e0, e1;
        e0 = a0[0].x * s; e1 = a0[0].y * s;
        asm("v_cvt_pk_bf16_f32 %0, %1, %2" : "=v"(p0) : "v"(e0), "v"(e1));
        e0 = a0[1].x * s; e1 = a0[1].y * s;
        asm("v_cvt_pk_bf16_f32 %0, %1, %2" : "=v"(p1) : "v"(e0), "v"(e1));
        e0 = a0[2].x * s; e1 = a0[2].y * s;
        asm("v_cvt_pk_bf16_f32 %0, %1, %2" : "=v"(p2) : "v"(e0), "v"(e1));
        e0 = a0[3].x * s; e1 = a0[3].y * s;
        asm("v_cvt_pk_bf16_f32 %0, %1, %2" : "=v"(p3) : "v"(e0), "v"(e1));
        uint4v pkt = (uint4v){p0, p1, p2, p3};
        __builtin_nontemporal_store(pkt,
            (uint4v*)(Abuf + (size_t)(sl * 9 + r) * SLs + (size_t)n * 32 + idx4 * 8));
    }
    if (v1) {
        float s = cnt1 > 0 ? 1.0f / (float)cnt1 : 0.f;
        const int r = (int)(((unsigned long long)seg1 * M) >> 48);
        const int n = seg1 - r * nN;
        unsigned p0, p1, p2, p3;
        float e0, e1;
        e0 = a1[0].x * s; e1 = a1[0].y * s;
        asm("v_cvt_pk_bf16_f32 %0, %1, %2" : "=v"(p0) : "v"(e0), "v"(e1));
        e0 = a1[1].x * s; e1 = a1[1].y * s;
        asm("v_cvt_pk_bf16_f32 %0, %1, %2" : "=v"(p1) : "v"(e0), "v"(e1));
        e0 = a1[2].x * s; e1 = a1[2].y * s;
        asm("v_cvt_pk_bf16_f32 %0, %1, %2" : "=v"(p2) : "v"(e0), "v"(e1));
        e0 = a1[3].x * s; e1 = a1[3].y * s;
        asm("v_cvt_pk_bf16_f32 %0, %1, %2" : "=v"(p3) : "v"(e0), "v"(e1));
        uint4v pkt = (uint4v){p0, p1, p2, p3};
        __builtin_nontemporal_store(pkt,
            (uint4v*)(Abuf + (size_t)(sl * 9 + r) * SLs + (size_t)n * 32 + idx4 * 8));
    }
}

// ---------- MFMA GEMM: M=nN, N=128, K=(nRel+1)*128 ----------
// A = Abuf [4 slices][9 slabs][nNalloc][32]; B = wB [nRel+1][128][128].
// Pipelined 2-phase: global_load_lds(16B) into linear LDS; st_8x16 XOR swizzle
// on the global SOURCE granule; ds_read applies the same XOR. The LDS image is
// identical to the row-major version — only per-lane source addresses changed:
// dims d = h*64 + gd*8 live at slice sl = h*2 + (gd>>2), inner off (gd&3)*8.
__global__ __launch_bounds__(256)
void rgcn_gemm_mfma(const unsigned short* __restrict__ A,
                    const unsigned short* __restrict__ wB,
                    const float* __restrict__ bias,
                    float* __restrict__ out, int nN, int nRel, size_t SLs) {
    __shared__ __align__(16) unsigned short As[2][64 * 64];    // [buf][row][64k]
    __shared__ __align__(16) unsigned short Bs[2][128 * 64];   // [buf][ocol][64k]
    const int tid = threadIdx.x;
    const int wave = tid >> 6;
    const int lane = tid & 63;
    const int wm = wave & 1;
    const int wn = wave >> 1;
    const int m16 = lane & 15;
    const int q = lane >> 4;
    const int row0 = blockIdx.x * 64;

    v4f acc[2][4];
#pragma unroll
    for (int i = 0; i < 2; i++)
#pragma unroll
        for (int j = 0; j < 4; j++) acc[i][j] = (v4f){0.f, 0.f, 0.f, 0.f};

    // ds_read offsets (ushort idx), swizzle: granule g read at slot g ^ (row&7)
    const int sw = m16 & 7;
    int aoff[2][2], boff[4][2];
#pragma unroll
    for (int mt = 0; mt < 2; mt++) {
        int row = wm * 32 + mt * 16 + m16;
#pragma unroll
        for (int kb = 0; kb < 2; kb++)
            aoff[mt][kb] = row * 64 + (((kb * 4 + q) ^ sw) * 8);
    }
#pragma unroll
    for (int nt = 0; nt < 4; nt++) {
        int o = wn * 64 + nt * 16 + m16;
#pragma unroll
        for (int kb = 0; kb < 2; kb++)
            boff[nt][kb] = o * 64 + (((kb * 4 + q) ^ sw) * 8);
    }

    // staging: lane l writes LDS slot (8 rows x 8 granule-slots); slot gs holds
    // source granule gd = gs ^ (row&7) = (l&7) ^ (l>>3).
    const int l8 = lane >> 3;
    const int gd = (lane & 7) ^ l8;
    // A source (sliced layout): slice = h*2 + (gd>>2); +s*SLs per step.
    const size_t aBaseH0 = (size_t)((gd >> 2) * 9) * SLs
                         + (size_t)(row0 + wave * 16 + l8) * 32 + (gd & 3) * 8;
    const size_t bBase = (size_t)(wave * 32 + l8) * D + gd * 8;   // wB row-major

    const int nT = 2 * (nRel + 1);    // 18 K-steps of 64

#define STAGE(buf, t) do { \
        const int s_ = (t) >> 1, h_ = (t) & 1; \
        const unsigned short* ga_ = A + aBaseH0 + (size_t)h_ * 18 * SLs + (size_t)s_ * SLs; \
        const unsigned short* gb_ = wB + (size_t)s_ * (D * D) + h_ * 64 + bBase; \
        GLOAD_LDS16(ga_,        &As[buf][(wave * 2 + 0) * 512]); \
        GLOAD_LDS16(ga_ + 256,  &As[buf][(wave * 2 + 1) * 512]); \
        GLOAD_LDS16(gb_,        &Bs[buf][(wave * 4 + 0) * 512]); \
        GLOAD_LDS16(gb_ + 1024, &Bs[buf][(wave * 4 + 1) * 512]); \
        GLOAD_LDS16(gb_ + 2048, &Bs[buf][(wave * 4 + 2) * 512]); \
        GLOAD_LDS16(gb_ + 3072, &Bs[buf][(wave * 4 + 3) * 512]); \
    } while (0)

    STAGE(0, 0);
    __syncthreads();                    // vmcnt(0) drain emitted by compiler
    int cur = 0;
    for (int t = 0; t < nT; ++t) {
        if (t + 1 < nT) STAGE(cur ^ 1, t + 1);   // next tile in flight over compute
        const unsigned short* Ab = As[cur];
        const unsigned short* Bb = Bs[cur];
        short8 a[2][2], b[4][2];
#pragma unroll
        for (int kb = 0; kb < 2; kb++) {
#pragma unroll
            for (int mt = 0; mt < 2; mt++)
                a[mt][kb] = *(const short8*)&Ab[aoff[mt][kb]];
#pragma unroll
            for (int nt = 0; nt < 4; nt++)
                b[nt][kb] = *(const short8*)&Bb[boff[nt][kb]];
        }
#pragma unroll
        for (int kb = 0; kb < 2; kb++)
#pragma unroll
            for (int mt = 0; mt < 2; mt++)
#pragma unroll
                for (int nt = 0; nt < 4; nt++)
                    acc[mt][nt] = __builtin_amdgcn_mfma_f32_16x16x32_bf16(
                        a[mt][kb], b[nt][kb], acc[mt][nt], 0, 0, 0);
        __syncthreads();
        cur ^= 1;
    }
#undef STAGE

#pragma unroll
    for (int mt = 0; mt < 2; mt++) {
#pragma unroll
        for (int nt = 0; nt < 4; nt++) {
            int col = wn * 64 + nt * 16 + m16;
            float bi = bias[col];
#pragma unroll
            for (int reg = 0; reg < 4; reg++) {
                int rrow = row0 + wm * 32 + mt * 16 + q * 4 + reg;
                if (rrow < nN)
                    out[(size_t)rrow * D + col] = acc[mt][nt][reg] + bi;
            }
        }
    }
}

extern "C" void kernel_launch(void* const* d_in, const int* in_sizes, int n_in,
                              void* d_out, int out_size, void* d_ws, size_t ws_size,
                              hipStream_t stream) {
    const float* x    = (const float*)d_in[0];
    const int*   ei   = (const int*)d_in[1];
    const int*   et   = (const int*)d_in[2];
    const float* w    = (const float*)d_in[3];
    const float* root = (const float*)d_in[4];
    const float* bias = (const float*)d_in[5];
    float* out = (float*)d_out;

    const int nN   = in_sizes[0] / D;        // 50000 (< 65536 for ushort dst)
    const int nE   = in_sizes[2];
    const int nRel = in_sizes[3] / (D * D);
    const int numSeg = nRel * nN;
    const int B = (numSeg + SEGS_PER_BUCKET - 1) >> SEG_BITS;   // 782 (<= 1024)
    const int nBH = B * NBLK;
    const int epb = (nE + NBLK - 1) / NBLK;
    const int nNalloc = (nN + 63) & ~63;     // pad rows to 64; garbage rows benign
    const size_t SLs = (size_t)nNalloc * 32; // elements per (slice, slab)
    const unsigned long long M = ((1ULL << 48) + nN - 1) / nN;  // magic for /nN

    // workspace layout (~133 MB; ws proven >= 218 MB)
    char* p = (char*)d_ws;
    unsigned* bucketEdges   = (unsigned*)p;        p += (size_t)nE * sizeof(unsigned);
    unsigned short* sortedDst = (unsigned short*)p; p += (size_t)nE * sizeof(unsigned short);
    p = (char*)(((uintptr_t)p + 255) & ~(uintptr_t)255);
    int* blockHist = (int*)p;  p += (size_t)nBH * sizeof(int);
    int* scanned   = (int*)p;  p += (size_t)nBH * sizeof(int);
    int* blockSums = (int*)p;  p += 256 * sizeof(int);
    p = (char*)(((uintptr_t)p + 255) & ~(uintptr_t)255);
    int4* permRec  = (int4*)p; p += (size_t)numSeg * sizeof(int4);
    int* permMax   = (int*)p;  p += (size_t)B * 32 * sizeof(int);
    p = (char*)(((uintptr_t)p + 255) & ~(uintptr_t)255);
    unsigned short* wBc  = (unsigned short*)p;  p += (size_t)(nRel + 1) * D * D * sizeof(unsigned short);
    p = (char*)(((uintptr_t)p + 255) & ~(uintptr_t)255);
    unsigned short* Abuf = (unsigned short*)p;     // [4][9][nNalloc][32]

    const int nScanBlocks = (nBH + SCAN_CHUNK - 1) / SCAN_CHUNK;  // 49 <= 256

    histA<<<NBLK, 256, 0, stream>>>(ei, et, blockHist, nE, nN, B, epb);
    scan1<<<nScanBlocks, 256, 0, stream>>>(blockHist, scanned, blockSums, nBH);
    scan2<<<1, 256, 0, stream>>>(blockSums, nScanBlocks);
    scatterA<<<NBLK, 256, 0, stream>>>(ei, et, scanned, blockSums, bucketEdges, nE, nN, B, epb);
    segOff<<<B, 256, 0, stream>>>(bucketEdges, scanned, blockSums, permRec, sortedDst, permMax,
                                  nE, numSeg, B);

    long long nx = (long long)nN * D;
    long long nw = (long long)nRel * D * D;
    long long nr = (long long)D * D;
    long long ncvt = (nx + nw + nr) / 4;
    cvt_bf16_all<<<(int)((ncvt + 255) / 256), 256, 0, stream>>>(x, nx, w, nw, root, nr,
                                                                Abuf, wBc, SLs);

    dim3 gg((numSeg + 127) / 128, 4);
    rgcn_gather<<<gg, 256, 0, stream>>>(Abuf, sortedDst, permRec, permMax, Abuf, nN, numSeg,
                                        SLs, M);

    rgcn_gemm_mfma<<<(nN + 63) / 64, 256, 0, stream>>>(Abuf, wBc, bias, out, nN, nRel, SLs);
}

// Round 8
// 225.733 us; speedup vs baseline: 1.2077x; 1.2077x over previous
//
#include <hip/hip_runtime.h>

// RGCN: bucketed atomic-free counting sort + block-local degree-binned
// dim-sliced bf16 gather + pipelined bf16 MFMA GEMM.
// Round-18 (attack the NON-gather 208us; gather untouched as control):
//   - GEMM: 128x128 tile (391 blocks, 4 waves, 64x64/wave, kb-outer frags):
//     32 MFMA per wave per barrier-pair (2x), half the barriers, same traffic.
//   - preprocessing: NBLK 128->256 (full CU coverage) + int4-vectorized edge
//     reads in histA/scatterA (epb rounded to x4 for alignment).
//   - gather/cvt/segOff byte-identical to R7 (attribution control).
//
//   seg(e) = rel(e)*nN + src(e)          (numSeg = nRel*nN)
//   agg[seg,:] = bf16( mean_{e in seg} x[dst_e,:] )
//   out = sum_r agg_r @ W_r^T + x @ root^T + bias   (MFMA 16x16x32 bf16)

#define D 128
#define SCAN_CHUNK 2048
#define SEG_BITS 9
#define SEGS_PER_BUCKET 512
#define NBLK 256            // blocks for histA/scatterA
#define NDEG 32             // degree buckets

typedef __attribute__((ext_vector_type(8))) short short8;
typedef __attribute__((ext_vector_type(4))) float v4f;
typedef __attribute__((ext_vector_type(2))) float f32x2;
typedef __attribute__((ext_vector_type(4))) unsigned uint4v;

#define GLOAD_LDS16(gptr, lptr) \
    __builtin_amdgcn_global_load_lds((const __attribute__((address_space(1))) void*)(gptr), \
                                     (__attribute__((address_space(3))) void*)(lptr), 16, 0, 0)

__device__ __forceinline__ unsigned short f2b(float f) {
    union { float f; unsigned u; } v; v.f = f;
    unsigned r = v.u + 0x7fffu + ((v.u >> 16) & 1u);   // RNE
    return (unsigned short)(r >> 16);
}
__device__ __forceinline__ float blo(unsigned u) {
    union { unsigned u; float f; } v; v.u = u << 16; return v.f;
}
__device__ __forceinline__ float bhi(unsigned u) {
    union { unsigned u; float f; } v; v.u = u & 0xffff0000u; return v.f;
}

// ---------- fp32 -> bf16 bulk convert ----------
// x goes to slab 8 of each slice of Abuf: addr = (sl*9 + 8)*SLs + n*32 + (d&31).
__global__ void cvt_bf16_all(const float* __restrict__ x, long long nx,
                             const float* __restrict__ w, long long nw,
                             const float* __restrict__ root, long long nr,
                             unsigned short* __restrict__ Abuf,
                             unsigned short* __restrict__ wB, size_t SLs) {
    long long i = ((long long)blockIdx.x * blockDim.x + threadIdx.x) * 4;
    if (i < nx) {
        float4 v = *(const float4*)(x + i);
        uint2 p;
        p.x = (unsigned)f2b(v.x) | ((unsigned)f2b(v.y) << 16);
        p.y = (unsigned)f2b(v.z) | ((unsigned)f2b(v.w) << 16);
        long long n = i >> 7;
        int d = (int)(i & 127);
        size_t o = (size_t)((d >> 5) * 9 + 8) * SLs + (size_t)n * 32 + (d & 31);
        *(uint2*)(Abuf + o) = p;
        return;
    }
    const float* src;
    unsigned short* dst;
    long long j;
    if (i < nx + nw) { src = w; dst = wB; j = i - nx; }
    else if (i < nx + nw + nr) { src = root; dst = wB + nw; j = i - nx - nw; }
    else return;
    float4 v = *(const float4*)(src + j);
    uint2 p;
    p.x = (unsigned)f2b(v.x) | ((unsigned)f2b(v.y) << 16);
    p.y = (unsigned)f2b(v.z) | ((unsigned)f2b(v.w) << 16);
    *(uint2*)(dst + j) = p;
}

// ---------- phase A: per-block bucket histogram (LDS atomics, int4 edges) ----------
__global__ __launch_bounds__(256)
void histA(const int* __restrict__ ei, const int* __restrict__ et,
           int* __restrict__ blockHist, int nE, int nN, int B, int epb) {
    __shared__ int lh[1024];
    const int tid = threadIdx.x;
    for (int b = tid; b < B; b += 256) lh[b] = 0;
    __syncthreads();
    const int base = blockIdx.x * epb;           // epb multiple of 4
    const int lim = min(base + epb, nE);
    for (int e = base + tid * 4; e < lim; e += 1024) {
        if (e + 4 <= lim) {
            int4 s = *(const int4*)(ei + e);
            int4 t = *(const int4*)(et + e);
            atomicAdd(&lh[(t.x * nN + s.x) >> SEG_BITS], 1);
            atomicAdd(&lh[(t.y * nN + s.y) >> SEG_BITS], 1);
            atomicAdd(&lh[(t.z * nN + s.z) >> SEG_BITS], 1);
            atomicAdd(&lh[(t.w * nN + s.w) >> SEG_BITS], 1);
        } else {
            for (int k = e; k < lim; k++)
                atomicAdd(&lh[(et[k] * nN + ei[k]) >> SEG_BITS], 1);
        }
    }
    __syncthreads();
    for (int b = tid; b < B; b += 256)
        blockHist[b * NBLK + blockIdx.x] = lh[b];
}

// ---------- scan of blockHist (bucket-major), 2 kernels + inline fixup ----------
__global__ __launch_bounds__(256)
void scan1(const int* __restrict__ in, int* __restrict__ excl,
           int* __restrict__ blockSums, int n) {
    __shared__ int t[256];
    const int tid = threadIdx.x;
    const int base = blockIdx.x * SCAN_CHUNK + tid * 8;
    int v[8];
    int tot = 0;
#pragma unroll
    for (int i = 0; i < 8; i++) {
        v[i] = (base + i < n) ? in[base + i] : 0;
        tot += v[i];
    }
    t[tid] = tot;
    __syncthreads();
    for (int off = 1; off < 256; off <<= 1) {
        int add = (tid >= off) ? t[tid - off] : 0;
        __syncthreads();
        t[tid] += add;
        __syncthreads();
    }
    int run = t[tid] - tot;
#pragma unroll
    for (int i = 0; i < 8; i++) {
        if (base + i < n) excl[base + i] = run;
        run += v[i];
    }
    if (tid == 255) blockSums[blockIdx.x] = t[255];
}

__global__ __launch_bounds__(256)
void scan2(int* __restrict__ blockSums, int nb) {
    __shared__ int t[256];
    const int tid = threadIdx.x;
    int v = (tid < nb) ? blockSums[tid] : 0;
    t[tid] = v;
    __syncthreads();
    for (int off = 1; off < 256; off <<= 1) {
        int add = (tid >= off) ? t[tid - off] : 0;
        __syncthreads();
        t[tid] += add;
        __syncthreads();
    }
    if (tid < nb) blockSums[tid] = t[tid] - v;
}

// ---------- phase C: bucket scatter (int4 edges, blockSums fix-up inline) ----------
__global__ __launch_bounds__(256)
void scatterA(const int* __restrict__ ei, const int* __restrict__ et,
              const int* __restrict__ scanned, const int* __restrict__ blockSums,
              unsigned* __restrict__ bucketEdges,
              int nE, int nN, int B, int epb) {
    __shared__ int cur[1024];
    const int tid = threadIdx.x;
    for (int b = tid; b < B; b += 256) {
        int idx = b * NBLK + blockIdx.x;
        cur[b] = scanned[idx] + blockSums[idx >> 11];   // SCAN_CHUNK = 2048
    }
    __syncthreads();
    const int base = blockIdx.x * epb;
    const int lim = min(base + epb, nE);
    for (int e = base + tid * 4; e < lim; e += 1024) {
        if (e + 4 <= lim) {
            int4 s = *(const int4*)(ei + e);
            int4 t = *(const int4*)(et + e);
            int4 d = *(const int4*)(ei + nE + e);
            int sg;
            sg = t.x * nN + s.x;
            bucketEdges[atomicAdd(&cur[sg >> SEG_BITS], 1)] =
                ((unsigned)(sg & (SEGS_PER_BUCKET - 1)) << 16) | (unsigned)d.x;
            sg = t.y * nN + s.y;
            bucketEdges[atomicAdd(&cur[sg >> SEG_BITS], 1)] =
                ((unsigned)(sg & (SEGS_PER_BUCKET - 1)) << 16) | (unsigned)d.y;
            sg = t.z * nN + s.z;
            bucketEdges[atomicAdd(&cur[sg >> SEG_BITS], 1)] =
                ((unsigned)(sg & (SEGS_PER_BUCKET - 1)) << 16) | (unsigned)d.z;
            sg = t.w * nN + s.w;
            bucketEdges[atomicAdd(&cur[sg >> SEG_BITS], 1)] =
                ((unsigned)(sg & (SEGS_PER_BUCKET - 1)) << 16) | (unsigned)d.w;
        } else {
            for (int k = e; k < lim; k++) {
                int sg = et[k] * nN + ei[k];
                bucketEdges[atomicAdd(&cur[sg >> SEG_BITS], 1)] =
                    ((unsigned)(sg & (SEGS_PER_BUCKET - 1)) << 16) | (unsigned)ei[nE + k];
            }
        }
    }
}

// ---------- phase D: seg offsets + sorted ushort dst + permRec/permMax ----------
__global__ __launch_bounds__(256)
void segOff(const unsigned* __restrict__ bucketEdges, const int* __restrict__ scanned,
            const int* __restrict__ blockSums,
            int4* __restrict__ permRec, unsigned short* __restrict__ sortedDst,
            int* __restrict__ permMax, int nE, int numSeg, int B) {
    __shared__ int lh[SEGS_PER_BUCKET];
    __shared__ int sc[256];
    __shared__ int lcur[SEGS_PER_BUCKET];
    __shared__ int dcnt[256];    // [sub 0..7][deg 0..31]
    __shared__ int dbase[256];
    __shared__ int smax[32];     // [sub 0..7][chunk 0..3] max degree
    const int tid = threadIdx.x;
    const int b = blockIdx.x;
    const int i0 = b * NBLK;
    const int eBase = scanned[i0] + blockSums[i0 >> 11];
    int eEnd = nE;
    if (b + 1 < B) {
        const int i1 = (b + 1) * NBLK;
        eEnd = scanned[i1] + blockSums[i1 >> 11];
    }
    const int segBase = b * SEGS_PER_BUCKET;
    const int segLim = min(SEGS_PER_BUCKET, numSeg - segBase);

    lh[2 * tid] = 0; lh[2 * tid + 1] = 0;
    dcnt[tid] = 0;
    if (tid < 32) smax[tid] = 0;
    __syncthreads();
    for (int i = eBase + tid; i < eEnd; i += 256)
        atomicAdd(&lh[bucketEdges[i] >> 16], 1);
    __syncthreads();
    const int li0 = 2 * tid, li1 = 2 * tid + 1;
    const int sub = li0 >> 6;            // 64-seg sub-window (== li1>>6)
    int a0 = lh[li0], a1 = lh[li1];
    int b0 = min(a0, NDEG - 1), b1 = min(a1, NDEG - 1), r0 = 0, r1 = 0;
    if (li0 < segLim) r0 = atomicAdd(&dcnt[sub * NDEG + b0], 1);
    if (li1 < segLim) r1 = atomicAdd(&dcnt[sub * NDEG + b1], 1);
    sc[tid] = a0 + a1;
    __syncthreads();
    for (int o = 1; o < 256; o <<= 1) {
        int add = (tid >= o) ? sc[tid - o] : 0;
        __syncthreads();
        sc[tid] += add;
        __syncthreads();
    }
    int pairBase = sc[tid] - (a0 + a1);
    int g0 = eBase + pairBase;
    int g1 = g0 + a0;
    lcur[li0] = g0;
    lcur[li1] = g1;
    if (tid < 8) {               // per-sub serial 32-prefix for bucket bases
        int run = 0;
#pragma unroll
        for (int k = 0; k < NDEG; k++) { dbase[tid * NDEG + k] = run; run += dcnt[tid * NDEG + k]; }
    }
    __syncthreads();
    if (li0 < segLim) {
        int rk = dbase[sub * NDEG + b0] + r0;           // rank within 64-window
        permRec[segBase + sub * 64 + rk] = make_int4(g0, a0, segBase + li0, 0);
        atomicMax(&smax[(sub << 2) + (rk >> 4)], a0);
    }
    if (li1 < segLim) {
        int rk = dbase[sub * NDEG + b1] + r1;
        permRec[segBase + sub * 64 + rk] = make_int4(g1, a1, segBase + li1, 0);
        atomicMax(&smax[(sub << 2) + (rk >> 4)], a1);
    }
    for (int i = eBase + tid; i < eEnd; i += 256) {
        unsigned u = bucketEdges[i];
        int pos = atomicAdd(&lcur[u >> 16], 1);
        sortedDst[pos] = (unsigned short)(u & 0xFFFFu);
    }
    __syncthreads();
    if (tid < 32) permMax[b * 32 + tid] = smax[tid];
}

// ---------- gather: 2 chunks/wave, dim-sliced, 4 lanes/edge (unchanged R7) ----------
__global__ __launch_bounds__(256)
void rgcn_gather(const unsigned short* __restrict__ Abase,
                 const unsigned short* __restrict__ sortedDst,
                 const int4* __restrict__ permRec,
                 const int* __restrict__ permMax,
                 unsigned short* __restrict__ Abuf, int nN, int numSeg,
                 size_t SLs, unsigned long long M) {
    const int tid = threadIdx.x;
    const int lane = tid & 63;
    const int idx4 = lane & 3;       // lane within 4-lane group (8 dims each)
    const int grp = lane >> 2;       // 16 groups per wave
    const int wv = tid >> 6;
    const int gsi0 = blockIdx.x * 128 + wv * 32 + grp;   // chunk 0 of this wave
    const int gsi1 = gsi0 + 16;                          // chunk 1
    const int sl = blockIdx.y;       // dims [sl*32, sl*32+32)
    const bool v0 = (gsi0 < numSeg);
    const bool v1 = (gsi1 < numSeg);

    int4 rc0 = v0 ? permRec[gsi0] : make_int4(0, 0, 0, 0);
    int4 rc1 = v1 ? permRec[gsi1] : make_int4(0, 0, 0, 0);
    int mx0 = v0 ? permMax[gsi0 >> 4] : 0;
    int mx1 = v1 ? permMax[gsi1 >> 4] : 0;
    mx0 = __builtin_amdgcn_readfirstlane(mx0);   // chunk-uniform -> scalar branch
    mx1 = __builtin_amdgcn_readfirstlane(mx1);

    const int start0 = rc0.x, cnt0 = v0 ? rc0.y : 0, seg0 = rc0.z;
    const int start1 = rc1.x, cnt1 = v1 ? rc1.y : 0, seg1 = rc1.z;

    f32x2 a0[4], a1[4];
#pragma unroll
    for (int i = 0; i < 4; i++) { a0[i] = (f32x2){0.f, 0.f}; a1[i] = (f32x2){0.f, 0.f}; }

    // x slab of this slice: slab 8 -> [n][32]; each lane owns 8 consecutive dims
    const unsigned short* xSlab = Abase + (size_t)(sl * 9 + 8) * SLs + idx4 * 8;

    const int mxm = max(mx0, mx1);
    for (int b = 0; b < mxm; b += 4) {
        uint4v w0[4], w1[4];
        int myD0 = 0, myD1 = 0;
        if (b < mx0) myD0 = (b + idx4 < cnt0) ? (int)sortedDst[start0 + b + idx4] : 0;
        if (b < mx1) myD1 = (b + idx4 < cnt1) ? (int)sortedDst[start1 + b + idx4] : 0;
        if (b < mx0) {
#pragma unroll
            for (int j = 0; j < 4; j++) {
                int dst = __shfl(myD0, grp * 4 + j);
                bool act = (b + j < cnt0);
                w0[j] = act ? *(const uint4v*)(xSlab + ((size_t)dst << 5))
                            : (uint4v){0u, 0u, 0u, 0u};
            }
        }
        if (b < mx1) {
#pragma unroll
            for (int j = 0; j < 4; j++) {
                int dst = __shfl(myD1, grp * 4 + j);
                bool act = (b + j < cnt1);
                w1[j] = act ? *(const uint4v*)(xSlab + ((size_t)dst << 5))
                            : (uint4v){0u, 0u, 0u, 0u};
            }
        }
        if (b < mx0) {
#pragma unroll
            for (int j = 0; j < 4; j++) {
                f32x2 t0 = (f32x2){blo(w0[j].x), bhi(w0[j].x)};
                f32x2 t1 = (f32x2){blo(w0[j].y), bhi(w0[j].y)};
                f32x2 t2 = (f32x2){blo(w0[j].z), bhi(w0[j].z)};
                f32x2 t3 = (f32x2){blo(w0[j].w), bhi(w0[j].w)};
                asm("v_pk_add_f32 %0, %0, %1" : "+v"(a0[0]) : "v"(t0));
                asm("v_pk_add_f32 %0, %0, %1" : "+v"(a0[1]) : "v"(t1));
                asm("v_pk_add_f32 %0, %0, %1" : "+v"(a0[2]) : "v"(t2));
                asm("v_pk_add_f32 %0, %0, %1" : "+v"(a0[3]) : "v"(t3));
            }
        }
        if (b < mx1) {
#pragma unroll
            for (int j = 0; j < 4; j++) {
                f32x2 t0 = (f32x2){blo(w1[j].x), bhi(w1[j].x)};
                f32x2 t1 = (f32x2){blo(w1[j].y), bhi(w1[j].y)};
                f32x2 t2 = (f32x2){blo(w1[j].z), bhi(w1[j].z)};
                f32x2 t3 = (f32x2){blo(w1[j].w), bhi(w1[j].w)};
                asm("v_pk_add_f32 %0, %0, %1" : "+v"(a1[0]) : "v"(t0));
                asm("v_pk_add_f32 %0, %0, %1" : "+v"(a1[1]) : "v"(t1));
                asm("v_pk_add_f32 %0, %0, %1" : "+v"(a1[2]) : "v"(t2));
                asm("v_pk_add_f32 %0, %0, %1" : "+v"(a1[3]) : "v"(t3));
            }
        }
    }

    if (v0) {
        float s = cnt0 > 0 ? 1.0f / (float)cnt0 : 0.f;
        const int r = (int)(((unsigned long long)seg0 * M) >> 48);  // seg / nN
        const int n = seg0 - r * nN;
        unsigned p0, p1, p2, p3;
        float e0, e1;
        e0 = a0[0].x * s; e1 = a0[0].y * s;
        asm("v_cvt_pk_bf16_f32 %0, %1, %2" : "=v"(p0) : "v"(e0), "v"(e1));
        e0 = a0[1].x * s; e1 = a0[1].y * s;
        asm("v_cvt_pk_bf16_f32 %0, %1, %2" : "=v"(p1) : "v"(e0), "v"(e1));
        e0 = a0[2].x * s; e1 = a0[2].y * s;
        asm("v_cvt_pk_bf16_f32 %0, %1, %2" : "=v"(p2) : "v"(e0), "v"(e1));
        e0 = a0[3].x * s; e1 = a0[3].y * s;
        asm("v_cvt_pk_bf16_f32 %0, %1, %2" : "=v"(p3) : "v"(e0), "v"(e1));
        uint4v pkt = (uint4v){p0, p1, p2, p3};
        __builtin_nontemporal_store(pkt,
            (uint4v*)(Abuf + (size_t)(sl * 9 + r) * SLs + (size_t)n * 32 + idx4 * 8));
    }
    if (v1) {
        float s = cnt1 > 0 ? 1.0f / (float)cnt1 : 0.f;
        const int r = (int)(((unsigned long long)seg1 * M) >> 48);
        const int n = seg1 - r * nN;
        unsigned p0, p1, p2, p3;
        float e0, e1;
        e0 = a1[0].x * s; e1 = a1[0].y * s;
        asm("v_cvt_pk_bf16_f32 %0, %1, %2" : "=v"(p0) : "v"(e0), "v"(e1));
        e0 = a1[1].x * s; e1 = a1[1].y * s;
        asm("v_cvt_pk_bf16_f32 %0, %1, %2" : "=v"(p1) : "v"(e0), "v"(e1));
        e0 = a1[2].x * s; e1 = a1[2].y * s;
        asm("v_cvt_pk_bf16_f32 %0, %1, %2" : "=v"(p2) : "v"(e0), "v"(e1));
        e0 = a1[3].x * s; e1 = a1[3].y * s;
        asm("v_cvt_pk_bf16_f32 %0, %1, %2" : "=v"(p3) : "v"(e0), "v"(e1));
        uint4v pkt = (uint4v){p0, p1, p2, p3};
        __builtin_nontemporal_store(pkt,
            (uint4v*)(Abuf + (size_t)(sl * 9 + r) * SLs + (size_t)n * 32 + idx4 * 8));
    }
}

// ---------- MFMA GEMM: 128x128 tile, M=nN, N=128, K=(nRel+1)*128 ----------
// A = Abuf [4 slices][9 slabs][nNalloc][32]; B = wB [nRel+1][128][128].
// 4 waves, each computes a 64x64 quadrant (4x4 16x16 frags, kb-outer).
// 2-phase pipelined global_load_lds with st_8x16 XOR swizzle on the SOURCE;
// 32 MFMA per wave between barrier pairs (2x the 64-tile version).
__global__ __launch_bounds__(256)
void rgcn_gemm_mfma(const unsigned short* __restrict__ A,
                    const unsigned short* __restrict__ wB,
                    const float* __restrict__ bias,
                    float* __restrict__ out, int nN, int nRel, size_t SLs) {
    __shared__ __align__(16) unsigned short As[2][128 * 64];   // [buf][row][64k]
    __shared__ __align__(16) unsigned short Bs[2][128 * 64];   // [buf][ocol][64k]
    const int tid = threadIdx.x;
    const int wave = tid >> 6;
    const int lane = tid & 63;
    const int wm = wave & 1;
    const int wn = wave >> 1;
    const int m16 = lane & 15;
    const int q = lane >> 4;
    const int row0 = blockIdx.x * 128;

    v4f acc[4][4];
#pragma unroll
    for (int i = 0; i < 4; i++)
#pragma unroll
        for (int j = 0; j < 4; j++) acc[i][j] = (v4f){0.f, 0.f, 0.f, 0.f};

    // ds_read offsets (ushort idx), swizzle: granule g read at slot g ^ (row&7)
    const int sw = m16 & 7;
    int aoff[4][2], boff[4][2];
#pragma unroll
    for (int mt = 0; mt < 4; mt++) {
        int row = wm * 64 + mt * 16 + m16;
#pragma unroll
        for (int kb = 0; kb < 2; kb++)
            aoff[mt][kb] = row * 64 + (((kb * 4 + q) ^ sw) * 8);
    }
#pragma unroll
    for (int nt = 0; nt < 4; nt++) {
        int o = wn * 64 + nt * 16 + m16;
#pragma unroll
        for (int kb = 0; kb < 2; kb++)
            boff[nt][kb] = o * 64 + (((kb * 4 + q) ^ sw) * 8);
    }

    // staging: lane l writes LDS slot (8 rows x 8 granule-slots); slot gs holds
    // source granule gd = gs ^ (row&7) = (l&7) ^ (l>>3).
    const int l8 = lane >> 3;
    const int gd = (lane & 7) ^ l8;
    // A source (sliced layout): slice = h*2 + (gd>>2); rows wave*32 + i*8 + l8.
    size_t aB[4];
#pragma unroll
    for (int i = 0; i < 4; i++)
        aB[i] = (size_t)((gd >> 2) * 9) * SLs
              + (size_t)(row0 + wave * 32 + i * 8 + l8) * 32 + (gd & 3) * 8;
    const size_t bBase = (size_t)(wave * 32 + l8) * D + gd * 8;   // wB row-major

    const int nT = 2 * (nRel + 1);    // 18 K-steps of 64

#define STAGE(buf, t) do { \
        const int s_ = (t) >> 1, h_ = (t) & 1; \
        const size_t hs_ = (size_t)h_ * 18 * SLs + (size_t)s_ * SLs; \
        const unsigned short* gb_ = wB + (size_t)s_ * (D * D) + h_ * 64 + bBase; \
        GLOAD_LDS16(A + aB[0] + hs_, &As[buf][(wave * 4 + 0) * 512]); \
        GLOAD_LDS16(A + aB[1] + hs_, &As[buf][(wave * 4 + 1) * 512]); \
        GLOAD_LDS16(A + aB[2] + hs_, &As[buf][(wave * 4 + 2) * 512]); \
        GLOAD_LDS16(A + aB[3] + hs_, &As[buf][(wave * 4 + 3) * 512]); \
        GLOAD_LDS16(gb_,        &Bs[buf][(wave * 4 + 0) * 512]); \
        GLOAD_LDS16(gb_ + 1024, &Bs[buf][(wave * 4 + 1) * 512]); \
        GLOAD_LDS16(gb_ + 2048, &Bs[buf][(wave * 4 + 2) * 512]); \
        GLOAD_LDS16(gb_ + 3072, &Bs[buf][(wave * 4 + 3) * 512]); \
    } while (0)

    STAGE(0, 0);
    __syncthreads();                    // vmcnt(0) drain emitted by compiler
    int cur = 0;
    for (int t = 0; t < nT; ++t) {
        if (t + 1 < nT) STAGE(cur ^ 1, t + 1);   // next tile in flight over compute
        const unsigned short* Ab = As[cur];
        const unsigned short* Bb = Bs[cur];
#pragma unroll
        for (int kb = 0; kb < 2; kb++) {
            short8 a[4], b[4];
#pragma unroll
            for (int mt = 0; mt < 4; mt++)
                a[mt] = *(const short8*)&Ab[aoff[mt][kb]];
#pragma unroll
            for (int nt = 0; nt < 4; nt++)
                b[nt] = *(const short8*)&Bb[boff[nt][kb]];
#pragma unroll
            for (int mt = 0; mt < 4; mt++)
#pragma unroll
                for (int nt = 0; nt < 4; nt++)
                    acc[mt][nt] = __builtin_amdgcn_mfma_f32_16x16x32_bf16(
                        a[mt], b[nt], acc[mt][nt], 0, 0, 0);
        }
        __syncthreads();
        cur ^= 1;
    }
#undef STAGE

#pragma unroll
    for (int mt = 0; mt < 4; mt++) {
#pragma unroll
        for (int nt = 0; nt < 4; nt++) {
            int col = wn * 64 + nt * 16 + m16;
            float bi = bias[col];
#pragma unroll
            for (int reg = 0; reg < 4; reg++) {
                int rrow = row0 + wm * 64 + mt * 16 + q * 4 + reg;
                if (rrow < nN)
                    out[(size_t)rrow * D + col] = acc[mt][nt][reg] + bi;
            }
        }
    }
}

extern "C" void kernel_launch(void* const* d_in, const int* in_sizes, int n_in,
                              void* d_out, int out_size, void* d_ws, size_t ws_size,
                              hipStream_t stream) {
    const float* x    = (const float*)d_in[0];
    const int*   ei   = (const int*)d_in[1];
    const int*   et   = (const int*)d_in[2];
    const float* w    = (const float*)d_in[3];
    const float* root = (const float*)d_in[4];
    const float* bias = (const float*)d_in[5];
    float* out = (float*)d_out;

    const int nN   = in_sizes[0] / D;        // 50000 (< 65536 for ushort dst)
    const int nE   = in_sizes[2];
    const int nRel = in_sizes[3] / (D * D);
    const int numSeg = nRel * nN;
    const int B = (numSeg + SEGS_PER_BUCKET - 1) >> SEG_BITS;   // 782 (<= 1024)
    const int nBH = B * NBLK;
    const int epb = (((nE + NBLK - 1) / NBLK) + 3) & ~3;        // mult of 4 (int4)
    const int nNalloc = (nN + 127) & ~127;   // pad rows to 128; garbage rows benign
    const size_t SLs = (size_t)nNalloc * 32; // elements per (slice, slab)
    const unsigned long long M = ((1ULL << 48) + nN - 1) / nN;  // magic for /nN

    // workspace layout (~134 MB; ws proven >= 218 MB)
    char* p = (char*)d_ws;
    unsigned* bucketEdges   = (unsigned*)p;        p += (size_t)nE * sizeof(unsigned);
    unsigned short* sortedDst = (unsigned short*)p; p += (size_t)nE * sizeof(unsigned short);
    p = (char*)(((uintptr_t)p + 255) & ~(uintptr_t)255);
    int* blockHist = (int*)p;  p += (size_t)nBH * sizeof(int);
    int* scanned   = (int*)p;  p += (size_t)nBH * sizeof(int);
    int* blockSums = (int*)p;  p += 256 * sizeof(int);
    p = (char*)(((uintptr_t)p + 255) & ~(uintptr_t)255);
    int4* permRec  = (int4*)p; p += (size_t)numSeg * sizeof(int4);
    int* permMax   = (int*)p;  p += (size_t)B * 32 * sizeof(int);
    p = (char*)(((uintptr_t)p + 255) & ~(uintptr_t)255);
    unsigned short* wBc  = (unsigned short*)p;  p += (size_t)(nRel + 1) * D * D * sizeof(unsigned short);
    p = (char*)(((uintptr_t)p + 255) & ~(uintptr_t)255);
    unsigned short* Abuf = (unsigned short*)p;     // [4][9][nNalloc][32]

    const int nScanBlocks = (nBH + SCAN_CHUNK - 1) / SCAN_CHUNK;  // 98 <= 256

    histA<<<NBLK, 256, 0, stream>>>(ei, et, blockHist, nE, nN, B, epb);
    scan1<<<nScanBlocks, 256, 0, stream>>>(blockHist, scanned, blockSums, nBH);
    scan2<<<1, 256, 0, stream>>>(blockSums, nScanBlocks);
    scatterA<<<NBLK, 256, 0, stream>>>(ei, et, scanned, blockSums, bucketEdges, nE, nN, B, epb);
    segOff<<<B, 256, 0, stream>>>(bucketEdges, scanned, blockSums, permRec, sortedDst, permMax,
                                  nE, numSeg, B);

    long long nx = (long long)nN * D;
    long long nw = (long long)nRel * D * D;
    long long nr = (long long)D * D;
    long long ncvt = (nx + nw + nr) / 4;
    cvt_bf16_all<<<(int)((ncvt + 255) / 256), 256, 0, stream>>>(x, nx, w, nw, root, nr,
                                                                Abuf, wBc, SLs);

    dim3 gg((numSeg + 127) / 128, 4);
    rgcn_gather<<<gg, 256, 0, stream>>>(Abuf, sortedDst, permRec, permMax, Abuf, nN, numSeg,
                                        SLs, M);

    rgcn_gemm_mfma<<<(nN + 127) / 128, 256, 0, stream>>>(Abuf, wBc, bias, out, nN, nRel, SLs);
}